// Round 13
// baseline (1081.578 us; speedup 1.0000x reference)
//
#include <hip/hip_runtime.h>
#include <hip/hip_bf16.h>
#include <cstddef>

#define BB 256
#define TT 224
#define II 224
#define HH 1024
#define OO 4

typedef __attribute__((ext_vector_type(8))) short short8;   // 8 bf16 (4 VGPRs)
typedef __attribute__((ext_vector_type(4))) float f32x4;    // MFMA accumulator
typedef unsigned short ushort_t;

// ---------------------------------------------------------------- helpers
__device__ __forceinline__ unsigned short bfbits(float v) {
    __hip_bfloat16 b = __float2bfloat16(v);
    union { __hip_bfloat16 b; unsigned short u; } cv; cv.b = b; return cv.u;
}
__device__ __forceinline__ float bffloat(unsigned short u) {
    union { unsigned short u; __hip_bfloat16 b; } cv; cv.u = u; return __bfloat162float(cv.b);
}

// asm VMEM: hot-loop VMEM is inline asm so counted vmcnt windows are exact.
#define LD128(d, p)      asm volatile("global_load_dwordx4 %0, %1, off" : "=v"(d) : "v"(p) : "memory")
#define LD128_SYS(d, p)  asm volatile("global_load_dwordx4 %0, %1, off sc0 sc1" : "=v"(d) : "v"(p) : "memory")
#define STD_SYS(p, v)    asm volatile("global_store_dword %0, %1, off sc0 sc1" :: "v"(p), "v"(v) : "memory")
#define WAIT_VM(n) do { asm volatile("s_waitcnt vmcnt(" #n ")" ::: "memory"); __builtin_amdgcn_sched_barrier(0); } while (0)

__device__ __forceinline__ void stflag(unsigned* p, unsigned v) {
    asm volatile("global_store_dword %0, %1, off sc0 sc1" :: "v"(p), "v"(v) : "memory");
}
__device__ __forceinline__ unsigned ldflag(const unsigned* p) {
    unsigned v;
    asm volatile("global_load_dword %0, %1, off sc0 sc1\n\ts_waitcnt vmcnt(0)"
                 : "=v"(v) : "v"(p) : "memory");
    return v;
}

// fast tanh: (1 - e^-2v)/(1 + e^-2v), clamped
__device__ __forceinline__ float fast_tanh(float v) {
    v = fminf(fmaxf(v, -15.f), 15.f);
    const float e = __expf(-2.f * v);
    return (1.f - e) * __builtin_amdgcn_rcpf(1.f + e);
}

#define MFMA(a, b, c) __builtin_amdgcn_mfma_f32_16x16x32_bf16(a, b, c, 0, 0, 0)

// ---------------------------------------------------------------- utility kernels
__global__ void zero_kernel(float* __restrict__ p, int n) {
    int i = blockIdx.x * blockDim.x + threadIdx.x;
    if (i < n) p[i] = 0.f;
}

__global__ __launch_bounds__(256) void split_hi_lo(
    const float* __restrict__ src, ushort_t* __restrict__ hi,
    ushort_t* __restrict__ lo, int n4)
{
    struct u4 { ushort_t v[4]; };
    const int stride = gridDim.x * blockDim.x;
    for (int i = blockIdx.x * blockDim.x + threadIdx.x; i < n4; i += stride) {
        float4 s = ((const float4*)src)[i];
        float vv[4] = {s.x, s.y, s.z, s.w};
        u4 h, l;
        #pragma unroll
        for (int j = 0; j < 4; ++j) {
            unsigned short hb = bfbits(vv[j]);
            h.v[j] = hb;
            l.v[j] = bfbits(vv[j] - bffloat(hb));
        }
        ((u4*)hi)[i] = h;
        ((u4*)lo)[i] = l;
    }
}

// ---------------------------------------------------------------- persistent RNN (R12)
// 256 WGs (cooperative, 1/CU) x 512 thr (8 waves). 16 row-groups x 16 col-blocks.
// W_hh slice (128 VGPR) asm-staged into registers once; x-projection folded
// in-step. h exchange group-local via MALL (sc0 sc1). R12: PER-WAVE producer
// flags (each wave signals right after its own store drain -> syncthreads off
// the signal path) + 4-deep h-buffer rotation (distance-4 WAR safety: transitive
// flag coupling bounds sibling lag to 1 step; writes at t touch buf[(t+1)%4],
// last read at t-2). Consumers poll the 16 per-wave flags of their 2 producer
// WGs, one flag per lane, single ballot.
__global__ __launch_bounds__(512, 2) void rnn_persist6(
    const ushort_t* __restrict__ xh,   const ushort_t* __restrict__ xl,
    const ushort_t* __restrict__ wihh, const ushort_t* __restrict__ wihl,
    const ushort_t* __restrict__ whhh, const ushort_t* __restrict__ whhl,
    ushort_t* h0h, ushort_t* h0l, ushort_t* h1h, ushort_t* h1l,
    ushort_t* h2h, ushort_t* h2l, ushort_t* h3h, ushort_t* h3l,
    const float* __restrict__ b_ih, const float* __restrict__ b_hh,
    float* __restrict__ h32, unsigned* __restrict__ flags)
{
    __shared__ float red[8][16][66];   // 33.8 KB

    const int tid = threadIdx.x;
    const int wv = tid >> 6, lane = tid & 63;
    const int row16 = lane & 15, kblk = lane >> 4;
    const int lid = blockIdx.x;
    const int rb = lid & 15;           // row-group: rows 16*rb..+15
    const int cb = lid >> 4;           // col-block: cols 64*cb..+63
    const int r0 = rb * 16, c0 = cb * 64;

    // ---- stage W_hh K-slice into registers via asm loads (once) ----
    short8 wh[4][4], wl[4][4];         // [n][kb]
    #pragma unroll
    for (int n = 0; n < 4; ++n) {
        const ushort_t* bh = whhh + (size_t)(c0 + n * 16 + row16) * HH + 128 * wv + kblk * 8;
        const ushort_t* bl = whhl + (size_t)(c0 + n * 16 + row16) * HH + 128 * wv + kblk * 8;
        LD128(wh[n][0], bh);      LD128(wh[n][1], bh + 32);
        LD128(wh[n][2], bh + 64); LD128(wh[n][3], bh + 96);
        LD128(wl[n][0], bl);      LD128(wl[n][1], bl + 32);
        LD128(wl[n][2], bl + 64); LD128(wl[n][3], bl + 96);
    }
    WAIT_VM(0);

    // epilogue mapping: thread = (row erow, col-pair ecp): 1 row x 2 adjacent cols
    const int erow = tid >> 5;         // 0..15
    const int ecp  = tid & 31;         // 0..31
    const int cg0  = c0 + 2 * ecp;
    const float bias0 = b_ih[cg0] + b_hh[cg0];
    const float bias1 = b_ih[cg0 + 1] + b_hh[cg0 + 1];

    const size_t ha = (size_t)(r0 + row16) * HH + 128 * wv + kblk * 8;
    const size_t xrow = (size_t)(r0 + row16) * TT;
    const size_t xcol = (size_t)wv * 32 + kblk * 8;

    // per-wave flag pointers: producer WG cbp = 2wv + (lane>>3), wave pwv = lane&7
    const int cbp = 2 * wv + (lane >> 3);
    const int pwv = lane & 7;
    const unsigned* fp = (lane < 16)
        ? flags + (((size_t)(cbp * 16 + rb) * 8 + pwv) << 4)
        : flags;
    unsigned* ourflag = flags + (((size_t)lid * 8 + wv) << 4);

    for (int t = 0; t < TT; ++t) {
        const int rp = t & 3, wp = (t + 1) & 3;
        const ushort_t* hph = (rp & 2) ? ((rp & 1) ? h3h : h2h) : ((rp & 1) ? h1h : h0h);
        const ushort_t* hpl = (rp & 2) ? ((rp & 1) ? h3l : h2l) : ((rp & 1) ? h1l : h0l);
        ushort_t* hnh = (wp & 2) ? ((wp & 1) ? h3h : h2h) : ((wp & 1) ? h1h : h0h);
        ushort_t* hnl = (wp & 2) ? ((wp & 1) ? h3l : h2l) : ((wp & 1) ? h1l : h0l);

        // ---- issue x + W_ih loads early: latency hides under the poll
        short8 fxh{}, fxl{}, wih_[4], wil_[4];
        if (wv < 7) {
            LD128(fxh, xh + (xrow + t) * II + xcol);
            LD128(fxl, xl + (xrow + t) * II + xcol);
            #pragma unroll
            for (int n = 0; n < 4; ++n) {
                LD128(wih_[n], wihh + (size_t)(c0 + n * 16 + row16) * II + xcol);
                LD128(wil_[n], wihl + (size_t)(c0 + n * 16 + row16) * II + xcol);
            }
        }

        // ---- per-wave poll: 16 producer-wave flags, one per lane
        if (t) {
            while (true) {
                unsigned vf = ldflag(fp);   // embedded vmcnt(0) also drains x loads
                const int ok = (lane < 16) ? (vf >= (unsigned)t) : 1;
                if (__ballot(ok) == ~0ull) break;
                __builtin_amdgcn_s_sleep(1);
            }
        }

        // ---- h loads, system scope (MALL)
        short8 fh[4], fl[4];
        {
            const ushort_t* ph = hph + ha;
            const ushort_t* pl = hpl + ha;
            LD128_SYS(fh[0], ph);      LD128_SYS(fl[0], pl);
            LD128_SYS(fh[1], ph + 32); LD128_SYS(fl[1], pl + 32);
            LD128_SYS(fh[2], ph + 64); LD128_SYS(fl[2], pl + 64);
            LD128_SYS(fh[3], ph + 96); LD128_SYS(fl[3], pl + 96);
        }

        f32x4 acc[4] = {};
        // ---- x-projection MFMAs overlap the h sys-load latency
        if (wv < 7) {
            WAIT_VM(8);    // x-side loads complete; 8 h loads outstanding
            #pragma unroll
            for (int n = 0; n < 4; ++n) {
                acc[n] = MFMA(fxh, wih_[n], acc[n]);
                acc[n] = MFMA(fxh, wil_[n], acc[n]);
                acc[n] = MFMA(fxl, wih_[n], acc[n]);
            }
        }
        __builtin_amdgcn_s_setprio(1);
        WAIT_VM(4);        // fh/fl kb0,kb1 ready
        #pragma unroll
        for (int kb = 0; kb < 2; ++kb)
            #pragma unroll
            for (int n = 0; n < 4; ++n) {
                acc[n] = MFMA(fh[kb], wh[n][kb], acc[n]);
                acc[n] = MFMA(fh[kb], wl[n][kb], acc[n]);
                acc[n] = MFMA(fl[kb], wh[n][kb], acc[n]);
            }
        WAIT_VM(0);        // kb2,kb3 ready
        #pragma unroll
        for (int kb = 2; kb < 4; ++kb)
            #pragma unroll
            for (int n = 0; n < 4; ++n) {
                acc[n] = MFMA(fh[kb], wh[n][kb], acc[n]);
                acc[n] = MFMA(fh[kb], wl[n][kb], acc[n]);
                acc[n] = MFMA(fl[kb], wh[n][kb], acc[n]);
            }
        __builtin_amdgcn_s_setprio(0);

        // ---- cross-wave K reduction
        #pragma unroll
        for (int n = 0; n < 4; ++n)
            #pragma unroll
            for (int jj = 0; jj < 4; ++jj)
                red[wv][kblk * 4 + jj][n * 16 + row16] = acc[n][jj];
        __syncthreads();

        // ---- epilogue: 1 row x 2 cols per thread, packed dword stores
        {
            float v0 = bias0, v1 = bias1;
            #pragma unroll
            for (int w = 0; w < 8; ++w) {
                float2 rv = *(const float2*)&red[w][erow][2 * ecp];
                v0 += rv.x; v1 += rv.y;
            }
            v0 = fast_tanh(v0);
            v1 = fast_tanh(v1);
            const size_t o = (size_t)(r0 + erow) * HH + cg0;
            const unsigned short hb0 = bfbits(v0), hb1 = bfbits(v1);
            const unsigned packh = (unsigned)hb0 | ((unsigned)hb1 << 16);
            const unsigned short lb0 = bfbits(v0 - bffloat(hb0));
            const unsigned short lb1 = bfbits(v1 - bffloat(hb1));
            const unsigned packl = (unsigned)lb0 | ((unsigned)lb1 << 16);
            STD_SYS(hnh + o, packh);
            STD_SYS(hnl + o, packl);
            if (t == TT - 1) { h32[o] = v0; h32[o + 1] = v1; }
        }

        WAIT_VM(0);                       // this wave's stores acked at MALL
        if (lane == 0) stflag(ourflag, (unsigned)(t + 1));   // signal immediately
        __syncthreads();                  // red-buffer reuse safety (off signal path)
    }
}

// ---------------------------------------------------------------- per-step fallback (coop launch fail)
__global__ __launch_bounds__(512) void rnn_step_f(
    const ushort_t* __restrict__ xh,   const ushort_t* __restrict__ xl,
    const ushort_t* __restrict__ wihh, const ushort_t* __restrict__ wihl,
    const ushort_t* __restrict__ whhh, const ushort_t* __restrict__ whhl,
    const ushort_t* __restrict__ hph,  const ushort_t* __restrict__ hpl,
    ushort_t* __restrict__ hnh, ushort_t* __restrict__ hnl,
    const float* __restrict__ b_ih, const float* __restrict__ b_hh,
    float* __restrict__ h32, int t)
{
    __shared__ float red[8][16][66];
    const int tid = threadIdx.x;
    const int wv = tid >> 6, lane = tid & 63;
    const int row16 = lane & 15, kblk = lane >> 4;
    const int lid = blockIdx.x;
    const int rb = lid & 15, cb = lid >> 4;
    const int r0 = rb * 16, c0 = cb * 64;
    const size_t xcol = (size_t)wv * 32 + kblk * 8;

    f32x4 acc[4] = {};
    if (wv < 7) {
        const size_t xo = ((size_t)(r0 + row16) * TT + t) * II + xcol;
        short8 fxh = *(const short8*)(xh + xo);
        short8 fxl = *(const short8*)(xl + xo);
        #pragma unroll
        for (int n = 0; n < 4; ++n) {
            const size_t wo = (size_t)(c0 + n * 16 + row16) * II + xcol;
            short8 wiH = *(const short8*)(wihh + wo);
            short8 wiL = *(const short8*)(wihl + wo);
            acc[n] = MFMA(fxh, wiH, acc[n]);
            acc[n] = MFMA(fxh, wiL, acc[n]);
            acc[n] = MFMA(fxl, wiH, acc[n]);
        }
    }
    const size_t ha = (size_t)(r0 + row16) * HH + 128 * wv + kblk * 8;
    #pragma unroll
    for (int kb = 0; kb < 4; ++kb) {
        short8 fH = *(const short8*)(hph + ha + kb * 32);
        short8 fL = *(const short8*)(hpl + ha + kb * 32);
        #pragma unroll
        for (int n = 0; n < 4; ++n) {
            const size_t wo = (size_t)(c0 + n * 16 + row16) * HH + 128 * wv + kb * 32 + kblk * 8;
            short8 wH = *(const short8*)(whhh + wo);
            short8 wL = *(const short8*)(whhl + wo);
            acc[n] = MFMA(fH, wH, acc[n]);
            acc[n] = MFMA(fH, wL, acc[n]);
            acc[n] = MFMA(fL, wH, acc[n]);
        }
    }
    #pragma unroll
    for (int n = 0; n < 4; ++n)
        #pragma unroll
        for (int jj = 0; jj < 4; ++jj)
            red[wv][kblk * 4 + jj][n * 16 + row16] = acc[n][jj];
    __syncthreads();
    {
        const int erow = tid >> 5;
        const int ecp  = tid & 31;
        const int cg0  = c0 + 2 * ecp;
        float v0 = b_ih[cg0] + b_hh[cg0];
        float v1 = b_ih[cg0 + 1] + b_hh[cg0 + 1];
        #pragma unroll
        for (int w = 0; w < 8; ++w) {
            float2 rv = *(const float2*)&red[w][erow][2 * ecp];
            v0 += rv.x; v1 += rv.y;
        }
        v0 = tanhf(v0); v1 = tanhf(v1);
        const size_t o = (size_t)(r0 + erow) * HH + cg0;
        const unsigned short hb0 = bfbits(v0), hb1 = bfbits(v1);
        hnh[o] = hb0;  hnh[o + 1] = hb1;
        hnl[o] = bfbits(v0 - bffloat(hb0));
        hnl[o + 1] = bfbits(v1 - bffloat(hb1));
        if (t == TT - 1) { h32[o] = v0; h32[o + 1] = v1; }
    }
}

// ---------------------------------------------------------------- FC
__global__ __launch_bounds__(256) void fc_kernel(
    const float* __restrict__ h, const float* __restrict__ W_fc,
    const float* __restrict__ b_fc, float* __restrict__ out)
{
    const int b = blockIdx.x;
    const int tid = threadIdx.x;
    float p[OO] = {0.f, 0.f, 0.f, 0.f};
    for (int k = tid; k < HH; k += 256) {
        float hv = h[(size_t)b * HH + k];
        #pragma unroll
        for (int o = 0; o < OO; ++o) p[o] += hv * W_fc[(size_t)o * HH + k];
    }
    #pragma unroll
    for (int off = 32; off > 0; off >>= 1) {
        #pragma unroll
        for (int o = 0; o < OO; ++o) p[o] += __shfl_down(p[o], off, 64);
    }
    __shared__ float red[4][OO];
    const int wave = tid >> 6, lane = tid & 63;
    if (lane == 0) {
        #pragma unroll
        for (int o = 0; o < OO; ++o) red[wave][o] = p[o];
    }
    __syncthreads();
    if (tid < OO) {
        float s = red[0][tid] + red[1][tid] + red[2][tid] + red[3][tid] + b_fc[tid];
        out[b * OO + tid] = s;
    }
}

// ---------------------------------------------------------------- launch
extern "C" void kernel_launch(void* const* d_in, const int* in_sizes, int n_in,
                              void* d_out, int out_size, void* d_ws, size_t ws_size,
                              hipStream_t stream) {
    const float* x    = (const float*)d_in[0];
    const float* W_ih = (const float*)d_in[1];
    const float* W_hh = (const float*)d_in[2];
    const float* b_ih = (const float*)d_in[3];
    const float* b_hh = (const float*)d_in[4];
    const float* W_fc = (const float*)d_in[5];
    const float* b_fc = (const float*)d_in[6];
    float* out = (float*)d_out;

    // ws layout (bytes)
    const size_t SZ_X   = (size_t)BB * TT * II * 2;   // 25.7 MB per plane
    const size_t SZ_WIH = (size_t)HH * II * 2;
    const size_t SZ_WHH = (size_t)HH * HH * 2;
    const size_t SZ_H   = (size_t)BB * HH * 2;        // 512 KB per h plane
    const size_t OFF_XH   = 0;
    const size_t OFF_XL   = OFF_XH + SZ_X;
    const size_t OFF_WIHH = OFF_XL + SZ_X;
    const size_t OFF_WIHL = OFF_WIHH + SZ_WIH;
    const size_t OFF_WHHH = OFF_WIHL + SZ_WIH;
    const size_t OFF_WHHL = OFF_WHHH + SZ_WHH;
    const size_t OFF_H0   = OFF_WHHL + SZ_WHH;        // 8 planes: h0h,h0l,h1h,...
    const size_t OFF_H32  = OFF_H0 + 8 * SZ_H;
    const size_t OFF_FLAGS = OFF_H32 + (size_t)BB * HH * 4;
    const size_t NEED      = OFF_FLAGS + 256 * 8 * 64;

    char* ws = (char*)d_ws;

    if (ws_size >= NEED) {
        ushort_t* xhp  = (ushort_t*)(ws + OFF_XH);
        ushort_t* xlp  = (ushort_t*)(ws + OFF_XL);
        ushort_t* wihh = (ushort_t*)(ws + OFF_WIHH);
        ushort_t* wihl = (ushort_t*)(ws + OFF_WIHL);
        ushort_t* whhh = (ushort_t*)(ws + OFF_WHHH);
        ushort_t* whhl = (ushort_t*)(ws + OFF_WHHL);
        ushort_t* hq[8];
        for (int i = 0; i < 8; ++i) hq[i] = (ushort_t*)(ws + OFF_H0 + (size_t)i * SZ_H);
        float*    h32  = (float*)(ws + OFF_H32);
        unsigned* flags = (unsigned*)(ws + OFF_FLAGS);

        // prep: hi/lo splits of x, W_ih, W_hh; zero h buf0 planes + flags
        split_hi_lo<<<1024, 256, 0, stream>>>(x, xhp, xlp, (BB * TT * II) / 4);
        split_hi_lo<<<128, 256, 0, stream>>>(W_ih, wihh, wihl, (HH * II) / 4);
        split_hi_lo<<<512, 256, 0, stream>>>(W_hh, whhh, whhl, (HH * HH) / 4);
        zero_kernel<<<(int)((2 * SZ_H / 4 + 255) / 256), 256, 0, stream>>>((float*)(ws + OFF_H0), (int)(2 * SZ_H / 4));
        zero_kernel<<<128, 256, 0, stream>>>((float*)flags, 256 * 8 * 16);

        const float* bihp = b_ih;
        const float* bhhp = b_hh;
        void* args[] = {
            (void*)&xhp, (void*)&xlp, (void*)&wihh, (void*)&wihl,
            (void*)&whhh, (void*)&whhl,
            (void*)&hq[0], (void*)&hq[1], (void*)&hq[2], (void*)&hq[3],
            (void*)&hq[4], (void*)&hq[5], (void*)&hq[6], (void*)&hq[7],
            (void*)&bihp, (void*)&bhhp, (void*)&h32, (void*)&flags
        };
        hipError_t e = hipLaunchCooperativeKernel((void*)rnn_persist6,
                                                  dim3(256), dim3(512), args, 0, stream);
        if (e != hipSuccess) {
            // fallback: per-step loop (kernel boundaries provide coherence)
            for (int t = 0; t < TT; ++t) {
                const int rp = t & 3, wp = (t + 1) & 3;
                rnn_step_f<<<256, 512, 0, stream>>>(
                    xhp, xlp, wihh, wihl, whhh, whhl,
                    hq[2 * rp], hq[2 * rp + 1], hq[2 * wp], hq[2 * wp + 1],
                    b_ih, b_hh, h32, t);
            }
        }
        fc_kernel<<<BB, 256, 0, stream>>>(h32, W_fc, b_fc, out);
    }
    // (ws too small not expected: NEED ~62 MB, observed ws ~268 MB)
}

// Round 15
// 943.897 us; speedup vs baseline: 1.1459x; 1.1459x over previous
//
#include <hip/hip_runtime.h>
#include <hip/hip_bf16.h>
#include <cstddef>

#define BB 256
#define TT 224
#define II 224
#define HH 1024
#define OO 4

typedef __attribute__((ext_vector_type(8))) short short8;   // 8 bf16 (4 VGPRs)
typedef __attribute__((ext_vector_type(4))) float f32x4;    // MFMA accumulator
typedef unsigned short ushort_t;

// ---------------------------------------------------------------- helpers
__device__ __forceinline__ unsigned short bfbits(float v) {
    __hip_bfloat16 b = __float2bfloat16(v);
    union { __hip_bfloat16 b; unsigned short u; } cv; cv.b = b; return cv.u;
}
__device__ __forceinline__ float bffloat(unsigned short u) {
    union { unsigned short u; __hip_bfloat16 b; } cv; cv.u = u; return __bfloat162float(cv.b);
}

// asm VMEM: hot-loop VMEM is inline asm so counted vmcnt windows are exact.
#define LD128(d, p)      asm volatile("global_load_dwordx4 %0, %1, off" : "=v"(d) : "v"(p) : "memory")
#define LD128_SYS(d, p)  asm volatile("global_load_dwordx4 %0, %1, off sc0 sc1" : "=v"(d) : "v"(p) : "memory")
#define STD_SYS(p, v)    asm volatile("global_store_dword %0, %1, off sc0 sc1" :: "v"(p), "v"(v) : "memory")
#define WAIT_VM(n) do { asm volatile("s_waitcnt vmcnt(" #n ")" ::: "memory"); __builtin_amdgcn_sched_barrier(0); } while (0)

__device__ __forceinline__ void stflag(unsigned* p, unsigned v) {
    asm volatile("global_store_dword %0, %1, off sc0 sc1" :: "v"(p), "v"(v) : "memory");
}
__device__ __forceinline__ unsigned ldflag(const unsigned* p) {
    unsigned v;
    asm volatile("global_load_dword %0, %1, off sc0 sc1\n\ts_waitcnt vmcnt(0)"
                 : "=v"(v) : "v"(p) : "memory");
    return v;
}

// fast tanh: (1 - e^-2v)/(1 + e^-2v), clamped
__device__ __forceinline__ float fast_tanh(float v) {
    v = fminf(fmaxf(v, -15.f), 15.f);
    const float e = __expf(-2.f * v);
    return (1.f - e) * __builtin_amdgcn_rcpf(1.f + e);
}

#define MFMA(a, b, c) __builtin_amdgcn_mfma_f32_16x16x32_bf16(a, b, c, 0, 0, 0)

// ---------------------------------------------------------------- utility kernels
__global__ void zero_kernel(float* __restrict__ p, int n) {
    int i = blockIdx.x * blockDim.x + threadIdx.x;
    if (i < n) p[i] = 0.f;
}

__global__ __launch_bounds__(256) void split_hi_lo(
    const float* __restrict__ src, ushort_t* __restrict__ hi,
    ushort_t* __restrict__ lo, int n4)
{
    struct u4 { ushort_t v[4]; };
    const int stride = gridDim.x * blockDim.x;
    for (int i = blockIdx.x * blockDim.x + threadIdx.x; i < n4; i += stride) {
        float4 s = ((const float4*)src)[i];
        float vv[4] = {s.x, s.y, s.z, s.w};
        u4 h, l;
        #pragma unroll
        for (int j = 0; j < 4; ++j) {
            unsigned short hb = bfbits(vv[j]);
            h.v[j] = hb;
            l.v[j] = bfbits(vv[j] - bffloat(hb));
        }
        ((u4*)hi)[i] = h;
        ((u4*)lo)[i] = l;
    }
}

// ---------------------------------------------------------------- persistent RNN (R14)
// 256 WGs (cooperative, 1/CU) x 512 thr (8 waves). 16 row-groups x 16 col-blocks.
// W_hh slice (hi+lo, 128 regs) asm-staged into registers once; x-projection
// folded in-step (3-term). h exchange group-local via MALL (sc0 sc1), **hi-plane
// bf16 only** (halves MALL read traffic; W keeps hi+lo so recurrent MFMA is
// 2-term AH*BH + AH*BL). Per-wave producer flags + 4-deep h rotation; red is
// double-buffered by t&1 so only ONE syncthreads per step (start-of-step poll
// is the cross-WG rendezvous; transitive flag coupling gives WAR safety).
__global__ __launch_bounds__(512, 2) void rnn_persist8(
    const ushort_t* __restrict__ xh,   const ushort_t* __restrict__ xl,
    const ushort_t* __restrict__ wihh, const ushort_t* __restrict__ wihl,
    const ushort_t* __restrict__ whhh, const ushort_t* __restrict__ whhl,
    ushort_t* h0, ushort_t* h1, ushort_t* h2, ushort_t* h3,
    const float* __restrict__ b_ih, const float* __restrict__ b_hh,
    float* __restrict__ h32, unsigned* __restrict__ flags)
{
    __shared__ float red[2][8][16][66];   // 67.6 KB, double-buffered by t&1

    const int tid = threadIdx.x;
    const int wv = tid >> 6, lane = tid & 63;
    const int row16 = lane & 15, kblk = lane >> 4;
    const int lid = blockIdx.x;
    const int rb = lid & 15;           // row-group: rows 16*rb..+15
    const int cb = lid >> 4;           // col-block: cols 64*cb..+63
    const int r0 = rb * 16, c0 = cb * 64;

    // ---- stage W_hh K-slice (hi+lo) into registers via asm loads (once) ----
    short8 wh[4][4], wl[4][4];         // [n][kb]
    #pragma unroll
    for (int n = 0; n < 4; ++n) {
        const ushort_t* bh = whhh + (size_t)(c0 + n * 16 + row16) * HH + 128 * wv + kblk * 8;
        const ushort_t* bl = whhl + (size_t)(c0 + n * 16 + row16) * HH + 128 * wv + kblk * 8;
        LD128(wh[n][0], bh);      LD128(wh[n][1], bh + 32);
        LD128(wh[n][2], bh + 64); LD128(wh[n][3], bh + 96);
        LD128(wl[n][0], bl);      LD128(wl[n][1], bl + 32);
        LD128(wl[n][2], bl + 64); LD128(wl[n][3], bl + 96);
    }
    WAIT_VM(0);

    // epilogue mapping: thread = (row erow, col-pair ecp): 1 row x 2 adjacent cols
    const int erow = tid >> 5;         // 0..15
    const int ecp  = tid & 31;         // 0..31
    const int cg0  = c0 + 2 * ecp;
    const float bias0 = b_ih[cg0] + b_hh[cg0];
    const float bias1 = b_ih[cg0 + 1] + b_hh[cg0 + 1];

    const size_t ha = (size_t)(r0 + row16) * HH + 128 * wv + kblk * 8;
    const size_t xrow = (size_t)(r0 + row16) * TT;
    const size_t xcol = (size_t)wv * 32 + kblk * 8;

    // per-wave flag pointers: producer WG cbp = 2wv + (lane>>3), wave pwv = lane&7
    const int cbp = 2 * wv + (lane >> 3);
    const int pwv = lane & 7;
    const unsigned* fp = (lane < 16)
        ? flags + (((size_t)(cbp * 16 + rb) * 8 + pwv) << 4)
        : flags;
    unsigned* ourflag = flags + (((size_t)lid * 8 + wv) << 4);

    for (int t = 0; t < TT; ++t) {
        const int rp = t & 3, wp = (t + 1) & 3;
        const ushort_t* hph = (rp & 2) ? ((rp & 1) ? h3 : h2) : ((rp & 1) ? h1 : h0);
        ushort_t*       hnh = (wp & 2) ? ((wp & 1) ? h3 : h2) : ((wp & 1) ? h1 : h0);

        // ---- issue x + W_ih loads early: latency hides under the poll
        short8 fxh{}, fxl{}, wih_[4], wil_[4];
        if (wv < 7) {
            LD128(fxh, xh + (xrow + t) * II + xcol);
            LD128(fxl, xl + (xrow + t) * II + xcol);
            #pragma unroll
            for (int n = 0; n < 4; ++n) {
                LD128(wih_[n], wihh + (size_t)(c0 + n * 16 + row16) * II + xcol);
                LD128(wil_[n], wihl + (size_t)(c0 + n * 16 + row16) * II + xcol);
            }
        }

        // ---- per-wave poll: 16 producer-wave flags, one per lane
        if (t) {
            while (true) {
                unsigned vf = ldflag(fp);   // embedded vmcnt(0) also drains x loads
                const int ok = (lane < 16) ? (vf >= (unsigned)t) : 1;
                if (__ballot(ok) == ~0ull) break;
                __builtin_amdgcn_s_sleep(1);
            }
        }

        // ---- h loads (hi plane only), system scope (MALL)
        short8 fh[4];
        {
            const ushort_t* ph = hph + ha;
            LD128_SYS(fh[0], ph);
            LD128_SYS(fh[1], ph + 32);
            LD128_SYS(fh[2], ph + 64);
            LD128_SYS(fh[3], ph + 96);
        }

        f32x4 acc[4] = {};
        // ---- x-projection MFMAs overlap the h sys-load latency
        if (wv < 7) {
            WAIT_VM(4);    // x-side loads complete; 4 h loads outstanding
            #pragma unroll
            for (int n = 0; n < 4; ++n) {
                acc[n] = MFMA(fxh, wih_[n], acc[n]);
                acc[n] = MFMA(fxh, wil_[n], acc[n]);
                acc[n] = MFMA(fxl, wih_[n], acc[n]);
            }
        }
        __builtin_amdgcn_s_setprio(1);
        WAIT_VM(2);        // fh kb0,kb1 ready
        #pragma unroll
        for (int kb = 0; kb < 2; ++kb)
            #pragma unroll
            for (int n = 0; n < 4; ++n) {
                acc[n] = MFMA(fh[kb], wh[n][kb], acc[n]);
                acc[n] = MFMA(fh[kb], wl[n][kb], acc[n]);
            }
        WAIT_VM(0);        // kb2,kb3 ready
        #pragma unroll
        for (int kb = 2; kb < 4; ++kb)
            #pragma unroll
            for (int n = 0; n < 4; ++n) {
                acc[n] = MFMA(fh[kb], wh[n][kb], acc[n]);
                acc[n] = MFMA(fh[kb], wl[n][kb], acc[n]);
            }
        __builtin_amdgcn_s_setprio(0);

        // ---- cross-wave K reduction (double-buffered by t&1)
        #pragma unroll
        for (int n = 0; n < 4; ++n)
            #pragma unroll
            for (int jj = 0; jj < 4; ++jj)
                red[t & 1][wv][kblk * 4 + jj][n * 16 + row16] = acc[n][jj];
        __syncthreads();   // the ONE barrier per step

        // ---- epilogue: 1 row x 2 cols per thread, packed dword store (hi only)
        {
            float v0 = bias0, v1 = bias1;
            #pragma unroll
            for (int w = 0; w < 8; ++w) {
                float2 rv = *(const float2*)&red[t & 1][w][erow][2 * ecp];
                v0 += rv.x; v1 += rv.y;
            }
            v0 = fast_tanh(v0);
            v1 = fast_tanh(v1);
            const size_t o = (size_t)(r0 + erow) * HH + cg0;
            const unsigned short hb0 = bfbits(v0), hb1 = bfbits(v1);
            const unsigned packh = (unsigned)hb0 | ((unsigned)hb1 << 16);
            STD_SYS(hnh + o, packh);
            if (t == TT - 1) { h32[o] = v0; h32[o + 1] = v1; }
        }

        WAIT_VM(0);                       // this wave's store acked at MALL
        if (lane == 0) stflag(ourflag, (unsigned)(t + 1));   // signal immediately
        // no trailing syncthreads: red is double-buffered; poll is the rendezvous
    }
}

// ---------------------------------------------------------------- per-step fallback (coop launch fail)
__global__ __launch_bounds__(512) void rnn_step_f(
    const ushort_t* __restrict__ xh,   const ushort_t* __restrict__ xl,
    const ushort_t* __restrict__ wihh, const ushort_t* __restrict__ wihl,
    const ushort_t* __restrict__ whhh, const ushort_t* __restrict__ whhl,
    const ushort_t* __restrict__ hph,  ushort_t* __restrict__ hnh,
    const float* __restrict__ b_ih, const float* __restrict__ b_hh,
    float* __restrict__ h32, int t)
{
    __shared__ float red[8][16][66];
    const int tid = threadIdx.x;
    const int wv = tid >> 6, lane = tid & 63;
    const int row16 = lane & 15, kblk = lane >> 4;
    const int lid = blockIdx.x;
    const int rb = lid & 15, cb = lid >> 4;
    const int r0 = rb * 16, c0 = cb * 64;
    const size_t xcol = (size_t)wv * 32 + kblk * 8;

    f32x4 acc[4] = {};
    if (wv < 7) {
        const size_t xo = ((size_t)(r0 + row16) * TT + t) * II + xcol;
        short8 fxh = *(const short8*)(xh + xo);
        short8 fxl = *(const short8*)(xl + xo);
        #pragma unroll
        for (int n = 0; n < 4; ++n) {
            const size_t wo = (size_t)(c0 + n * 16 + row16) * II + xcol;
            short8 wiH = *(const short8*)(wihh + wo);
            short8 wiL = *(const short8*)(wihl + wo);
            acc[n] = MFMA(fxh, wiH, acc[n]);
            acc[n] = MFMA(fxh, wiL, acc[n]);
            acc[n] = MFMA(fxl, wiH, acc[n]);
        }
    }
    const size_t ha = (size_t)(r0 + row16) * HH + 128 * wv + kblk * 8;
    #pragma unroll
    for (int kb = 0; kb < 4; ++kb) {
        short8 fH = *(const short8*)(hph + ha + kb * 32);
        #pragma unroll
        for (int n = 0; n < 4; ++n) {
            const size_t wo = (size_t)(c0 + n * 16 + row16) * HH + 128 * wv + kb * 32 + kblk * 8;
            short8 wH = *(const short8*)(whhh + wo);
            short8 wL = *(const short8*)(whhl + wo);
            acc[n] = MFMA(fH, wH, acc[n]);
            acc[n] = MFMA(fH, wL, acc[n]);
        }
    }
    #pragma unroll
    for (int n = 0; n < 4; ++n)
        #pragma unroll
        for (int jj = 0; jj < 4; ++jj)
            red[wv][kblk * 4 + jj][n * 16 + row16] = acc[n][jj];
    __syncthreads();
    {
        const int erow = tid >> 5;
        const int ecp  = tid & 31;
        const int cg0  = c0 + 2 * ecp;
        float v0 = b_ih[cg0] + b_hh[cg0];
        float v1 = b_ih[cg0 + 1] + b_hh[cg0 + 1];
        #pragma unroll
        for (int w = 0; w < 8; ++w) {
            float2 rv = *(const float2*)&red[w][erow][2 * ecp];
            v0 += rv.x; v1 += rv.y;
        }
        v0 = tanhf(v0); v1 = tanhf(v1);
        const size_t o = (size_t)(r0 + erow) * HH + cg0;
        hnh[o] = bfbits(v0);  hnh[o + 1] = bfbits(v1);
        if (t == TT - 1) { h32[o] = v0; h32[o + 1] = v1; }
    }
}

// ---------------------------------------------------------------- FC
__global__ __launch_bounds__(256) void fc_kernel(
    const float* __restrict__ h, const float* __restrict__ W_fc,
    const float* __restrict__ b_fc, float* __restrict__ out)
{
    const int b = blockIdx.x;
    const int tid = threadIdx.x;
    float p[OO] = {0.f, 0.f, 0.f, 0.f};
    for (int k = tid; k < HH; k += 256) {
        float hv = h[(size_t)b * HH + k];
        #pragma unroll
        for (int o = 0; o < OO; ++o) p[o] += hv * W_fc[(size_t)o * HH + k];
    }
    #pragma unroll
    for (int off = 32; off > 0; off >>= 1) {
        #pragma unroll
        for (int o = 0; o < OO; ++o) p[o] += __shfl_down(p[o], off, 64);
    }
    __shared__ float red[4][OO];
    const int wave = tid >> 6, lane = tid & 63;
    if (lane == 0) {
        #pragma unroll
        for (int o = 0; o < OO; ++o) red[wave][o] = p[o];
    }
    __syncthreads();
    if (tid < OO) {
        float s = red[0][tid] + red[1][tid] + red[2][tid] + red[3][tid] + b_fc[tid];
        out[b * OO + tid] = s;
    }
}

// ---------------------------------------------------------------- launch
extern "C" void kernel_launch(void* const* d_in, const int* in_sizes, int n_in,
                              void* d_out, int out_size, void* d_ws, size_t ws_size,
                              hipStream_t stream) {
    const float* x    = (const float*)d_in[0];
    const float* W_ih = (const float*)d_in[1];
    const float* W_hh = (const float*)d_in[2];
    const float* b_ih = (const float*)d_in[3];
    const float* b_hh = (const float*)d_in[4];
    const float* W_fc = (const float*)d_in[5];
    const float* b_fc = (const float*)d_in[6];
    float* out = (float*)d_out;

    // ws layout (bytes)
    const size_t SZ_X   = (size_t)BB * TT * II * 2;   // 25.7 MB per plane
    const size_t SZ_WIH = (size_t)HH * II * 2;
    const size_t SZ_WHH = (size_t)HH * HH * 2;
    const size_t SZ_H   = (size_t)BB * HH * 2;        // 512 KB per h plane
    const size_t OFF_XH   = 0;
    const size_t OFF_XL   = OFF_XH + SZ_X;
    const size_t OFF_WIHH = OFF_XL + SZ_X;
    const size_t OFF_WIHL = OFF_WIHH + SZ_WIH;
    const size_t OFF_WHHH = OFF_WIHL + SZ_WIH;
    const size_t OFF_WHHL = OFF_WHHH + SZ_WHH;
    const size_t OFF_H0   = OFF_WHHL + SZ_WHH;        // 4 hi planes
    const size_t OFF_H32  = OFF_H0 + 4 * SZ_H;
    const size_t OFF_FLAGS = OFF_H32 + (size_t)BB * HH * 4;
    const size_t NEED      = OFF_FLAGS + 256 * 8 * 64;

    char* ws = (char*)d_ws;

    if (ws_size >= NEED) {
        ushort_t* xhp  = (ushort_t*)(ws + OFF_XH);
        ushort_t* xlp  = (ushort_t*)(ws + OFF_XL);
        ushort_t* wihh = (ushort_t*)(ws + OFF_WIHH);
        ushort_t* wihl = (ushort_t*)(ws + OFF_WIHL);
        ushort_t* whhh = (ushort_t*)(ws + OFF_WHHH);
        ushort_t* whhl = (ushort_t*)(ws + OFF_WHHL);
        ushort_t* hq[4];
        for (int i = 0; i < 4; ++i) hq[i] = (ushort_t*)(ws + OFF_H0 + (size_t)i * SZ_H);
        float*    h32  = (float*)(ws + OFF_H32);
        unsigned* flags = (unsigned*)(ws + OFF_FLAGS);

        // prep: hi/lo splits; zero h buf0 (hi) + flags (replay-safe: in-graph)
        split_hi_lo<<<1024, 256, 0, stream>>>(x, xhp, xlp, (BB * TT * II) / 4);
        split_hi_lo<<<128, 256, 0, stream>>>(W_ih, wihh, wihl, (HH * II) / 4);
        split_hi_lo<<<512, 256, 0, stream>>>(W_hh, whhh, whhl, (HH * HH) / 4);
        zero_kernel<<<(int)((SZ_H / 4 + 255) / 256), 256, 0, stream>>>((float*)(ws + OFF_H0), (int)(SZ_H / 4));
        zero_kernel<<<128, 256, 0, stream>>>((float*)flags, 256 * 8 * 16);

        const float* bihp = b_ih;
        const float* bhhp = b_hh;
        void* args[] = {
            (void*)&xhp, (void*)&xlp, (void*)&wihh, (void*)&wihl,
            (void*)&whhh, (void*)&whhl,
            (void*)&hq[0], (void*)&hq[1], (void*)&hq[2], (void*)&hq[3],
            (void*)&bihp, (void*)&bhhp, (void*)&h32, (void*)&flags
        };
        hipError_t e = hipLaunchCooperativeKernel((void*)rnn_persist8,
                                                  dim3(256), dim3(512), args, 0, stream);
        if (e != hipSuccess) {
            // fallback: per-step loop (kernel boundaries provide coherence)
            for (int t = 0; t < TT; ++t) {
                const int rp = t & 3, wp = (t + 1) & 3;
                rnn_step_f<<<256, 512, 0, stream>>>(
                    xhp, xlp, wihh, wihl, whhh, whhl,
                    hq[rp], hq[wp], b_ih, b_hh, h32, t);
            }
        }
        fc_kernel<<<BB, 256, 0, stream>>>(h32, W_fc, b_fc, out);
    }
    // (ws too small not expected: NEED ~58 MB, observed ws ~268 MB)
}

// Round 16
// 855.515 us; speedup vs baseline: 1.2642x; 1.1033x over previous
//
#include <hip/hip_runtime.h>
#include <hip/hip_bf16.h>
#include <cstddef>

#define BB 256
#define TT 224
#define II 224
#define HH 1024
#define OO 4
#define HPLANE ((size_t)BB * HH)          // elements per h plane (bf16 hi only)

typedef __attribute__((ext_vector_type(8))) short short8;   // 8 bf16 (4 VGPRs)
typedef __attribute__((ext_vector_type(4))) float f32x4;    // MFMA accumulator
typedef __attribute__((ext_vector_type(4))) unsigned uintx4;
typedef unsigned short ushort_t;

// ---------------------------------------------------------------- helpers
__device__ __forceinline__ unsigned short bfbits(float v) {
    __hip_bfloat16 b = __float2bfloat16(v);
    union { __hip_bfloat16 b; unsigned short u; } cv; cv.b = b; return cv.u;
}
__device__ __forceinline__ float bffloat(unsigned short u) {
    union { unsigned short u; __hip_bfloat16 b; } cv; cv.u = u; return __bfloat162float(cv.b);
}

// asm VMEM: hot-loop VMEM is inline asm so vmcnt windows are exact.
#define LD128(d, p)      asm volatile("global_load_dwordx4 %0, %1, off" : "=v"(d) : "v"(p) : "memory")
#define LD128_SYS(d, p)  asm volatile("global_load_dwordx4 %0, %1, off sc0 sc1" : "=v"(d) : "v"(p) : "memory")
#define STD_SYS(p, v)    asm volatile("global_store_dword %0, %1, off sc0 sc1" :: "v"(p), "v"(v) : "memory")
#define WAIT_VM(n) do { asm volatile("s_waitcnt vmcnt(" #n ")" ::: "memory"); __builtin_amdgcn_sched_barrier(0); } while (0)

// fast tanh: (1 - e^-2v)/(1 + e^-2v), clamped
__device__ __forceinline__ float fast_tanh(float v) {
    v = fminf(fmaxf(v, -15.f), 15.f);
    const float e = __expf(-2.f * v);
    return (1.f - e) * __builtin_amdgcn_rcpf(1.f + e);
}

#define MFMA(a, b, c) __builtin_amdgcn_mfma_f32_16x16x32_bf16(a, b, c, 0, 0, 0)

// ---------------------------------------------------------------- utility kernels
__global__ void zero_kernel(float* __restrict__ p, int n) {
    int i = blockIdx.x * blockDim.x + threadIdx.x;
    if (i < n) p[i] = 0.f;
}

// fill n4 uint4s with sentinel 0xFFFFFFFF (bf16 -NaN pairs: tanh never produces it)
__global__ void fill_sentinel(uintx4* __restrict__ p, size_t n4) {
    size_t i = (size_t)blockIdx.x * blockDim.x + threadIdx.x;
    const size_t stride = (size_t)gridDim.x * blockDim.x;
    const uintx4 s = {0xFFFFFFFFu, 0xFFFFFFFFu, 0xFFFFFFFFu, 0xFFFFFFFFu};
    for (; i < n4; i += stride) p[i] = s;
}

__global__ __launch_bounds__(256) void split_hi_lo(
    const float* __restrict__ src, ushort_t* __restrict__ hi,
    ushort_t* __restrict__ lo, int n4)
{
    struct u4 { ushort_t v[4]; };
    const int stride = gridDim.x * blockDim.x;
    for (int i = blockIdx.x * blockDim.x + threadIdx.x; i < n4; i += stride) {
        float4 s = ((const float4*)src)[i];
        float vv[4] = {s.x, s.y, s.z, s.w};
        u4 h, l;
        #pragma unroll
        for (int j = 0; j < 4; ++j) {
            unsigned short hb = bfbits(vv[j]);
            h.v[j] = hb;
            l.v[j] = bfbits(vv[j] - bffloat(hb));
        }
        ((u4*)hi)[i] = h;
        ((u4*)lo)[i] = l;
    }
}

// ---------------------------------------------------------------- persistent RNN (R15)
// 256 WGs (cooperative, 1/CU) x 512 thr (8 waves). 16 row-groups x 16 col-blocks.
// W_hh slice (hi+lo) register-resident; x-projection folded in-step; h hi-plane
// bf16 only. R15: 225 DISTINCT h planes (no reuse -> no WAR, unlimited group
// skew) pre-filled with 0xFFFFFFFF sentinel; consumers POLL THE DATA ITSELF
// (each packed dword is stored atomically; tanh output is never bf16 0xFFFF).
// No flags, no producer store-drain, no counted vmcnt: the poll's vmcnt(0)
// drains everything. One syncthreads/step (red double-buffered by t&1).
__global__ __launch_bounds__(512, 2) void rnn_persist9(
    const ushort_t* __restrict__ xh,   const ushort_t* __restrict__ xl,
    const ushort_t* __restrict__ wihh, const ushort_t* __restrict__ wihl,
    const ushort_t* __restrict__ whhh, const ushort_t* __restrict__ whhl,
    ushort_t* __restrict__ hbuf,       // 225 planes of BB*HH bf16
    const float* __restrict__ b_ih, const float* __restrict__ b_hh,
    float* __restrict__ h32)
{
    __shared__ float red[2][8][16][66];   // 67.6 KB, double-buffered by t&1

    const int tid = threadIdx.x;
    const int wv = tid >> 6, lane = tid & 63;
    const int row16 = lane & 15, kblk = lane >> 4;
    const int lid = blockIdx.x;
    const int rb = lid & 15;           // row-group: rows 16*rb..+15
    const int cb = lid >> 4;           // col-block: cols 64*cb..+63
    const int r0 = rb * 16, c0 = cb * 64;

    // ---- stage W_hh K-slice (hi+lo) into registers via asm loads (once) ----
    short8 wh[4][4], wl[4][4];         // [n][kb]
    #pragma unroll
    for (int n = 0; n < 4; ++n) {
        const ushort_t* bh = whhh + (size_t)(c0 + n * 16 + row16) * HH + 128 * wv + kblk * 8;
        const ushort_t* bl = whhl + (size_t)(c0 + n * 16 + row16) * HH + 128 * wv + kblk * 8;
        LD128(wh[n][0], bh);      LD128(wh[n][1], bh + 32);
        LD128(wh[n][2], bh + 64); LD128(wh[n][3], bh + 96);
        LD128(wl[n][0], bl);      LD128(wl[n][1], bl + 32);
        LD128(wl[n][2], bl + 64); LD128(wl[n][3], bl + 96);
    }
    WAIT_VM(0);

    // epilogue mapping: thread = (row erow, col-pair ecp): 1 row x 2 adjacent cols
    const int erow = tid >> 5;         // 0..15
    const int ecp  = tid & 31;         // 0..31
    const int cg0  = c0 + 2 * ecp;
    const float bias0 = b_ih[cg0] + b_hh[cg0];
    const float bias1 = b_ih[cg0 + 1] + b_hh[cg0 + 1];

    const size_t ha = (size_t)(r0 + row16) * HH + 128 * wv + kblk * 8;
    const size_t xrow = (size_t)(r0 + row16) * TT;
    const size_t xcol = (size_t)wv * 32 + kblk * 8;

    for (int t = 0; t < TT; ++t) {
        const ushort_t* hph = hbuf + (size_t)t * HPLANE;        // read plane t
        ushort_t*       hnh = hbuf + (size_t)(t + 1) * HPLANE;  // write plane t+1

        // ---- issue x + W_ih loads early: drained by the poll's vmcnt(0)
        short8 fxh{}, fxl{}, wih_[4], wil_[4];
        if (wv < 7) {
            LD128(fxh, xh + (xrow + t) * II + xcol);
            LD128(fxl, xl + (xrow + t) * II + xcol);
            #pragma unroll
            for (int n = 0; n < 4; ++n) {
                LD128(wih_[n], wihh + (size_t)(c0 + n * 16 + row16) * II + xcol);
                LD128(wil_[n], wihl + (size_t)(c0 + n * 16 + row16) * II + xcol);
            }
        }

        // ---- poll-load h (hi plane): fresh iff no dword equals the sentinel
        short8 fh[4];
        {
            const ushort_t* ph = hph + ha;
            if (t) {
                while (true) {
                    LD128_SYS(fh[0], ph);      LD128_SYS(fh[1], ph + 32);
                    LD128_SYS(fh[2], ph + 64); LD128_SYS(fh[3], ph + 96);
                    WAIT_VM(0);
                    unsigned ok = 1u;
                    #pragma unroll
                    for (int k = 0; k < 4; ++k) {
                        uintx4 q = __builtin_bit_cast(uintx4, fh[k]);
                        ok &= (q[0] != 0xFFFFFFFFu) & (q[1] != 0xFFFFFFFFu) &
                              (q[2] != 0xFFFFFFFFu) & (q[3] != 0xFFFFFFFFu);
                    }
                    if (__ballot(ok) == ~0ull) break;
                    __builtin_amdgcn_s_sleep(1);
                }
            } else {
                LD128_SYS(fh[0], ph);      LD128_SYS(fh[1], ph + 32);
                LD128_SYS(fh[2], ph + 64); LD128_SYS(fh[3], ph + 96);
                WAIT_VM(0);
            }
        }

        // ---- MFMAs (everything already in registers)
        f32x4 acc[4] = {};
        if (wv < 7) {
            #pragma unroll
            for (int n = 0; n < 4; ++n) {
                acc[n] = MFMA(fxh, wih_[n], acc[n]);
                acc[n] = MFMA(fxh, wil_[n], acc[n]);
                acc[n] = MFMA(fxl, wih_[n], acc[n]);
            }
        }
        __builtin_amdgcn_s_setprio(1);
        #pragma unroll
        for (int kb = 0; kb < 4; ++kb)
            #pragma unroll
            for (int n = 0; n < 4; ++n) {
                acc[n] = MFMA(fh[kb], wh[n][kb], acc[n]);
                acc[n] = MFMA(fh[kb], wl[n][kb], acc[n]);
            }
        __builtin_amdgcn_s_setprio(0);

        // ---- cross-wave K reduction (double-buffered by t&1)
        #pragma unroll
        for (int n = 0; n < 4; ++n)
            #pragma unroll
            for (int jj = 0; jj < 4; ++jj)
                red[t & 1][wv][kblk * 4 + jj][n * 16 + row16] = acc[n][jj];
        __syncthreads();   // the ONE barrier per step

        // ---- epilogue: 1 row x 2 cols per thread, packed dword store (hi only)
        {
            float v0 = bias0, v1 = bias1;
            #pragma unroll
            for (int w = 0; w < 8; ++w) {
                float2 rv = *(const float2*)&red[t & 1][w][erow][2 * ecp];
                v0 += rv.x; v1 += rv.y;
            }
            v0 = fast_tanh(v0);
            v1 = fast_tanh(v1);
            const size_t o = (size_t)(r0 + erow) * HH + cg0;
            const unsigned short hb0 = bfbits(v0), hb1 = bfbits(v1);
            const unsigned packh = (unsigned)hb0 | ((unsigned)hb1 << 16);
            STD_SYS(hnh + o, packh);
            if (t == TT - 1) { h32[o] = v0; h32[o + 1] = v1; }
        }
        // no drain, no flag: consumers poll the stored data; next step's poll
        // vmcnt(0) drains this store on our own wave.
    }
}

// ---------------------------------------------------------------- per-step fallback (coop launch fail)
__global__ __launch_bounds__(512) void rnn_step_f(
    const ushort_t* __restrict__ xh,   const ushort_t* __restrict__ xl,
    const ushort_t* __restrict__ wihh, const ushort_t* __restrict__ wihl,
    const ushort_t* __restrict__ whhh, const ushort_t* __restrict__ whhl,
    const ushort_t* __restrict__ hph,  ushort_t* __restrict__ hnh,
    const float* __restrict__ b_ih, const float* __restrict__ b_hh,
    float* __restrict__ h32, int t)
{
    __shared__ float red[8][16][66];
    const int tid = threadIdx.x;
    const int wv = tid >> 6, lane = tid & 63;
    const int row16 = lane & 15, kblk = lane >> 4;
    const int lid = blockIdx.x;
    const int rb = lid & 15, cb = lid >> 4;
    const int r0 = rb * 16, c0 = cb * 64;
    const size_t xcol = (size_t)wv * 32 + kblk * 8;

    f32x4 acc[4] = {};
    if (wv < 7) {
        const size_t xo = ((size_t)(r0 + row16) * TT + t) * II + xcol;
        short8 fxh = *(const short8*)(xh + xo);
        short8 fxl = *(const short8*)(xl + xo);
        #pragma unroll
        for (int n = 0; n < 4; ++n) {
            const size_t wo = (size_t)(c0 + n * 16 + row16) * II + xcol;
            short8 wiH = *(const short8*)(wihh + wo);
            short8 wiL = *(const short8*)(wihl + wo);
            acc[n] = MFMA(fxh, wiH, acc[n]);
            acc[n] = MFMA(fxh, wiL, acc[n]);
            acc[n] = MFMA(fxl, wiH, acc[n]);
        }
    }
    const size_t ha = (size_t)(r0 + row16) * HH + 128 * wv + kblk * 8;
    #pragma unroll
    for (int kb = 0; kb < 4; ++kb) {
        short8 fH = *(const short8*)(hph + ha + kb * 32);
        #pragma unroll
        for (int n = 0; n < 4; ++n) {
            const size_t wo = (size_t)(c0 + n * 16 + row16) * HH + 128 * wv + kb * 32 + kblk * 8;
            short8 wH = *(const short8*)(whhh + wo);
            short8 wL = *(const short8*)(whhl + wo);
            acc[n] = MFMA(fH, wH, acc[n]);
            acc[n] = MFMA(fH, wL, acc[n]);
        }
    }
    #pragma unroll
    for (int n = 0; n < 4; ++n)
        #pragma unroll
        for (int jj = 0; jj < 4; ++jj)
            red[wv][kblk * 4 + jj][n * 16 + row16] = acc[n][jj];
    __syncthreads();
    {
        const int erow = tid >> 5;
        const int ecp  = tid & 31;
        const int cg0  = c0 + 2 * ecp;
        float v0 = b_ih[cg0] + b_hh[cg0];
        float v1 = b_ih[cg0 + 1] + b_hh[cg0 + 1];
        #pragma unroll
        for (int w = 0; w < 8; ++w) {
            float2 rv = *(const float2*)&red[w][erow][2 * ecp];
            v0 += rv.x; v1 += rv.y;
        }
        v0 = tanhf(v0); v1 = tanhf(v1);
        const size_t o = (size_t)(r0 + erow) * HH + cg0;
        hnh[o] = bfbits(v0);  hnh[o + 1] = bfbits(v1);
        if (t == TT - 1) { h32[o] = v0; h32[o + 1] = v1; }
    }
}

// ---------------------------------------------------------------- FC
__global__ __launch_bounds__(256) void fc_kernel(
    const float* __restrict__ h, const float* __restrict__ W_fc,
    const float* __restrict__ b_fc, float* __restrict__ out)
{
    const int b = blockIdx.x;
    const int tid = threadIdx.x;
    float p[OO] = {0.f, 0.f, 0.f, 0.f};
    for (int k = tid; k < HH; k += 256) {
        float hv = h[(size_t)b * HH + k];
        #pragma unroll
        for (int o = 0; o < OO; ++o) p[o] += hv * W_fc[(size_t)o * HH + k];
    }
    #pragma unroll
    for (int off = 32; off > 0; off >>= 1) {
        #pragma unroll
        for (int o = 0; o < OO; ++o) p[o] += __shfl_down(p[o], off, 64);
    }
    __shared__ float red[4][OO];
    const int wave = tid >> 6, lane = tid & 63;
    if (lane == 0) {
        #pragma unroll
        for (int o = 0; o < OO; ++o) red[wave][o] = p[o];
    }
    __syncthreads();
    if (tid < OO) {
        float s = red[0][tid] + red[1][tid] + red[2][tid] + red[3][tid] + b_fc[tid];
        out[b * OO + tid] = s;
    }
}

// ---------------------------------------------------------------- launch
extern "C" void kernel_launch(void* const* d_in, const int* in_sizes, int n_in,
                              void* d_out, int out_size, void* d_ws, size_t ws_size,
                              hipStream_t stream) {
    const float* x    = (const float*)d_in[0];
    const float* W_ih = (const float*)d_in[1];
    const float* W_hh = (const float*)d_in[2];
    const float* b_ih = (const float*)d_in[3];
    const float* b_hh = (const float*)d_in[4];
    const float* W_fc = (const float*)d_in[5];
    const float* b_fc = (const float*)d_in[6];
    float* out = (float*)d_out;

    // ws layout (bytes)
    const size_t SZ_X    = (size_t)BB * TT * II * 2;     // 25.7 MB per plane
    const size_t SZ_WIH  = (size_t)HH * II * 2;
    const size_t SZ_WHH  = (size_t)HH * HH * 2;
    const size_t SZ_HP   = HPLANE * 2;                   // 512 KB per h plane
    const size_t OFF_XH   = 0;
    const size_t OFF_XL   = OFF_XH + SZ_X;
    const size_t OFF_WIHH = OFF_XL + SZ_X;
    const size_t OFF_WIHL = OFF_WIHH + SZ_WIH;
    const size_t OFF_WHHH = OFF_WIHL + SZ_WIH;
    const size_t OFF_WHHL = OFF_WHHH + SZ_WHH;
    const size_t OFF_HBUF = OFF_WHHL + SZ_WHH;           // 225 planes
    const size_t OFF_H32  = OFF_HBUF + (size_t)(TT + 1) * SZ_HP;
    const size_t NEED     = OFF_H32 + (size_t)BB * HH * 4;

    char* ws = (char*)d_ws;

    if (ws_size >= NEED) {
        ushort_t* xhp  = (ushort_t*)(ws + OFF_XH);
        ushort_t* xlp  = (ushort_t*)(ws + OFF_XL);
        ushort_t* wihh = (ushort_t*)(ws + OFF_WIHH);
        ushort_t* wihl = (ushort_t*)(ws + OFF_WIHL);
        ushort_t* whhh = (ushort_t*)(ws + OFF_WHHH);
        ushort_t* whhl = (ushort_t*)(ws + OFF_WHHL);
        ushort_t* hbuf = (ushort_t*)(ws + OFF_HBUF);
        float*    h32  = (float*)(ws + OFF_H32);

        // prep: hi/lo splits; plane 0 = zeros (initial h); planes 1..224 = sentinel
        split_hi_lo<<<1024, 256, 0, stream>>>(x, xhp, xlp, (BB * TT * II) / 4);
        split_hi_lo<<<128, 256, 0, stream>>>(W_ih, wihh, wihl, (HH * II) / 4);
        split_hi_lo<<<512, 256, 0, stream>>>(W_hh, whhh, whhl, (HH * HH) / 4);
        zero_kernel<<<(int)((SZ_HP / 4 + 255) / 256), 256, 0, stream>>>((float*)hbuf, (int)(SZ_HP / 4));
        fill_sentinel<<<2048, 256, 0, stream>>>((uintx4*)(hbuf + HPLANE),
                                                (size_t)TT * SZ_HP / 16);

        const float* bihp = b_ih;
        const float* bhhp = b_hh;
        void* args[] = {
            (void*)&xhp, (void*)&xlp, (void*)&wihh, (void*)&wihl,
            (void*)&whhh, (void*)&whhl, (void*)&hbuf,
            (void*)&bihp, (void*)&bhhp, (void*)&h32
        };
        hipError_t e = hipLaunchCooperativeKernel((void*)rnn_persist9,
                                                  dim3(256), dim3(512), args, 0, stream);
        if (e != hipSuccess) {
            // fallback: per-step loop (kernel boundaries provide coherence;
            // sentinel planes are fully overwritten before being read)
            for (int t = 0; t < TT; ++t) {
                rnn_step_f<<<256, 512, 0, stream>>>(
                    xhp, xlp, wihh, wihl, whhh, whhl,
                    hbuf + (size_t)t * HPLANE, hbuf + (size_t)(t + 1) * HPLANE,
                    b_ih, b_hh, h32, t);
            }
        }
        fc_kernel<<<BB, 256, 0, stream>>>(h32, W_fc, b_fc, out);
    }
    // (ws too small not expected: NEED ~176 MB, observed ws ~268 MB)
}

// Round 17
// 788.556 us; speedup vs baseline: 1.3716x; 1.0849x over previous
//
#include <hip/hip_runtime.h>
#include <hip/hip_bf16.h>
#include <cstddef>

#define BB 256
#define TT 224
#define II 224
#define HH 1024
#define OO 4
#define HPLANE ((size_t)BB * HH)          // elements per h plane (bf16 hi only)

typedef __attribute__((ext_vector_type(8))) short short8;   // 8 bf16 (4 VGPRs)
typedef __attribute__((ext_vector_type(4))) float f32x4;    // MFMA accumulator
typedef __attribute__((ext_vector_type(4))) unsigned uintx4;
typedef unsigned short ushort_t;

// ---------------------------------------------------------------- helpers
__device__ __forceinline__ unsigned short bfbits(float v) {
    __hip_bfloat16 b = __float2bfloat16(v);
    union { __hip_bfloat16 b; unsigned short u; } cv; cv.b = b; return cv.u;
}
__device__ __forceinline__ float bffloat(unsigned short u) {
    union { unsigned short u; __hip_bfloat16 b; } cv; cv.u = u; return __bfloat162float(cv.b);
}

// asm VMEM: hot-loop VMEM is inline asm so vmcnt windows are exact.
#define LD128(d, p)      asm volatile("global_load_dwordx4 %0, %1, off" : "=v"(d) : "v"(p) : "memory")
#define LD128_SYS(d, p)  asm volatile("global_load_dwordx4 %0, %1, off sc0 sc1" : "=v"(d) : "v"(p) : "memory")
#define STD_SYS(p, v)    asm volatile("global_store_dword %0, %1, off sc0 sc1" :: "v"(p), "v"(v) : "memory")
#define WAIT_VM(n) do { asm volatile("s_waitcnt vmcnt(" #n ")" ::: "memory"); __builtin_amdgcn_sched_barrier(0); } while (0)

// fast tanh: (1 - e^-2v)/(1 + e^-2v), clamped
__device__ __forceinline__ float fast_tanh(float v) {
    v = fminf(fmaxf(v, -15.f), 15.f);
    const float e = __expf(-2.f * v);
    return (1.f - e) * __builtin_amdgcn_rcpf(1.f + e);
}

__device__ __forceinline__ unsigned fresh2(short8 a, short8 b) {
    uintx4 qa = __builtin_bit_cast(uintx4, a);
    uintx4 qb = __builtin_bit_cast(uintx4, b);
    return (qa[0] != 0xFFFFFFFFu) & (qa[1] != 0xFFFFFFFFu) &
           (qa[2] != 0xFFFFFFFFu) & (qa[3] != 0xFFFFFFFFu) &
           (qb[0] != 0xFFFFFFFFu) & (qb[1] != 0xFFFFFFFFu) &
           (qb[2] != 0xFFFFFFFFu) & (qb[3] != 0xFFFFFFFFu);
}

#define MFMA(a, b, c) __builtin_amdgcn_mfma_f32_16x16x32_bf16(a, b, c, 0, 0, 0)

// ---------------------------------------------------------------- utility kernels
__global__ void zero_kernel(float* __restrict__ p, int n) {
    int i = blockIdx.x * blockDim.x + threadIdx.x;
    if (i < n) p[i] = 0.f;
}

// fill n4 uint4s with sentinel 0xFFFFFFFF (bf16 -NaN pairs: tanh never produces it)
__global__ void fill_sentinel(uintx4* __restrict__ p, size_t n4) {
    size_t i = (size_t)blockIdx.x * blockDim.x + threadIdx.x;
    const size_t stride = (size_t)gridDim.x * blockDim.x;
    const uintx4 s = {0xFFFFFFFFu, 0xFFFFFFFFu, 0xFFFFFFFFu, 0xFFFFFFFFu};
    for (; i < n4; i += stride) p[i] = s;
}

__global__ __launch_bounds__(256) void split_hi_lo(
    const float* __restrict__ src, ushort_t* __restrict__ hi,
    ushort_t* __restrict__ lo, int n4)
{
    struct u4 { ushort_t v[4]; };
    const int stride = gridDim.x * blockDim.x;
    for (int i = blockIdx.x * blockDim.x + threadIdx.x; i < n4; i += stride) {
        float4 s = ((const float4*)src)[i];
        float vv[4] = {s.x, s.y, s.z, s.w};
        u4 h, l;
        #pragma unroll
        for (int j = 0; j < 4; ++j) {
            unsigned short hb = bfbits(vv[j]);
            h.v[j] = hb;
            l.v[j] = bfbits(vv[j] - bffloat(hb));
        }
        ((u4*)hi)[i] = h;
        ((u4*)lo)[i] = l;
    }
}

// ---------------------------------------------------------------- persistent RNN (R16)
// R15 + split-by-producer poll: chunks kb0-1 come from col-block 2wv, kb2-3
// from 2wv+1. Poll A (half the retry bytes) -> issue B -> x-proj + kb0-1 MFMAs
// hide B's RTT -> check B (retry re-issues only 2 chunks) -> kb2-3 MFMAs.
// Retry backoff s_sleep(2) trims the MALL burst at arrival time.
__global__ __launch_bounds__(512, 2) void rnn_persist10(
    const ushort_t* __restrict__ xh,   const ushort_t* __restrict__ xl,
    const ushort_t* __restrict__ wihh, const ushort_t* __restrict__ wihl,
    const ushort_t* __restrict__ whhh, const ushort_t* __restrict__ whhl,
    ushort_t* __restrict__ hbuf,       // 225 planes of BB*HH bf16
    const float* __restrict__ b_ih, const float* __restrict__ b_hh,
    float* __restrict__ h32)
{
    __shared__ float red[2][8][16][66];   // 67.6 KB, double-buffered by t&1

    const int tid = threadIdx.x;
    const int wv = tid >> 6, lane = tid & 63;
    const int row16 = lane & 15, kblk = lane >> 4;
    const int lid = blockIdx.x;
    const int rb = lid & 15;           // row-group: rows 16*rb..+15
    const int cb = lid >> 4;           // col-block: cols 64*cb..+63
    const int r0 = rb * 16, c0 = cb * 64;

    // ---- stage W_hh K-slice (hi+lo) into registers via asm loads (once) ----
    short8 wh[4][4], wl[4][4];         // [n][kb]
    #pragma unroll
    for (int n = 0; n < 4; ++n) {
        const ushort_t* bh = whhh + (size_t)(c0 + n * 16 + row16) * HH + 128 * wv + kblk * 8;
        const ushort_t* bl = whhl + (size_t)(c0 + n * 16 + row16) * HH + 128 * wv + kblk * 8;
        LD128(wh[n][0], bh);      LD128(wh[n][1], bh + 32);
        LD128(wh[n][2], bh + 64); LD128(wh[n][3], bh + 96);
        LD128(wl[n][0], bl);      LD128(wl[n][1], bl + 32);
        LD128(wl[n][2], bl + 64); LD128(wl[n][3], bl + 96);
    }
    WAIT_VM(0);

    // epilogue mapping: thread = (row erow, col-pair ecp): 1 row x 2 adjacent cols
    const int erow = tid >> 5;         // 0..15
    const int ecp  = tid & 31;         // 0..31
    const int cg0  = c0 + 2 * ecp;
    const float bias0 = b_ih[cg0] + b_hh[cg0];
    const float bias1 = b_ih[cg0 + 1] + b_hh[cg0 + 1];

    const size_t ha = (size_t)(r0 + row16) * HH + 128 * wv + kblk * 8;
    const size_t xrow = (size_t)(r0 + row16) * TT;
    const size_t xcol = (size_t)wv * 32 + kblk * 8;

    for (int t = 0; t < TT; ++t) {
        const ushort_t* hph = hbuf + (size_t)t * HPLANE;        // read plane t
        ushort_t*       hnh = hbuf + (size_t)(t + 1) * HPLANE;  // write plane t+1

        // ---- issue x + W_ih loads early: drained by poll A's vmcnt(0)
        short8 fxh{}, fxl{}, wih_[4], wil_[4];
        if (wv < 7) {
            LD128(fxh, xh + (xrow + t) * II + xcol);
            LD128(fxl, xl + (xrow + t) * II + xcol);
            #pragma unroll
            for (int n = 0; n < 4; ++n) {
                LD128(wih_[n], wihh + (size_t)(c0 + n * 16 + row16) * II + xcol);
                LD128(wil_[n], wihl + (size_t)(c0 + n * 16 + row16) * II + xcol);
            }
        }

        const ushort_t* ph = hph + ha;
        short8 fh[4];
        f32x4 acc[4] = {};

        // ---- poll A: chunks kb0,kb1 (producer col-block 2wv)
        {
            LD128_SYS(fh[0], ph);  LD128_SYS(fh[1], ph + 32);
            WAIT_VM(0);
            if (t) {
                int first = 1;
                while (__ballot(fresh2(fh[0], fh[1])) != ~0ull) {
                    if (!first) __builtin_amdgcn_s_sleep(2);
                    first = 0;
                    LD128_SYS(fh[0], ph);  LD128_SYS(fh[1], ph + 32);
                    WAIT_VM(0);
                }
            }
        }

        // ---- issue B's loads (kb2,kb3: producer col-block 2wv+1) now;
        //      x-proj + kb0-1 MFMAs hide their latency
        LD128_SYS(fh[2], ph + 64);  LD128_SYS(fh[3], ph + 96);

        if (wv < 7) {
            #pragma unroll
            for (int n = 0; n < 4; ++n) {
                acc[n] = MFMA(fxh, wih_[n], acc[n]);
                acc[n] = MFMA(fxh, wil_[n], acc[n]);
                acc[n] = MFMA(fxl, wih_[n], acc[n]);
            }
        }
        __builtin_amdgcn_s_setprio(1);
        #pragma unroll
        for (int kb = 0; kb < 2; ++kb)
            #pragma unroll
            for (int n = 0; n < 4; ++n) {
                acc[n] = MFMA(fh[kb], wh[n][kb], acc[n]);
                acc[n] = MFMA(fh[kb], wl[n][kb], acc[n]);
            }
        __builtin_amdgcn_s_setprio(0);

        // ---- poll B: check (usually fresh); retry re-issues only 2 chunks
        {
            WAIT_VM(0);
            if (t) {
                while (__ballot(fresh2(fh[2], fh[3])) != ~0ull) {
                    __builtin_amdgcn_s_sleep(2);
                    LD128_SYS(fh[2], ph + 64);  LD128_SYS(fh[3], ph + 96);
                    WAIT_VM(0);
                }
            }
        }
        __builtin_amdgcn_s_setprio(1);
        #pragma unroll
        for (int kb = 2; kb < 4; ++kb)
            #pragma unroll
            for (int n = 0; n < 4; ++n) {
                acc[n] = MFMA(fh[kb], wh[n][kb], acc[n]);
                acc[n] = MFMA(fh[kb], wl[n][kb], acc[n]);
            }
        __builtin_amdgcn_s_setprio(0);

        // ---- cross-wave K reduction (double-buffered by t&1)
        #pragma unroll
        for (int n = 0; n < 4; ++n)
            #pragma unroll
            for (int jj = 0; jj < 4; ++jj)
                red[t & 1][wv][kblk * 4 + jj][n * 16 + row16] = acc[n][jj];
        __syncthreads();   // the ONE barrier per step

        // ---- epilogue: 1 row x 2 cols per thread, packed dword store (hi only)
        {
            float v0 = bias0, v1 = bias1;
            #pragma unroll
            for (int w = 0; w < 8; ++w) {
                float2 rv = *(const float2*)&red[t & 1][w][erow][2 * ecp];
                v0 += rv.x; v1 += rv.y;
            }
            v0 = fast_tanh(v0);
            v1 = fast_tanh(v1);
            const size_t o = (size_t)(r0 + erow) * HH + cg0;
            const unsigned short hb0 = bfbits(v0), hb1 = bfbits(v1);
            const unsigned packh = (unsigned)hb0 | ((unsigned)hb1 << 16);
            STD_SYS(hnh + o, packh);
            if (t == TT - 1) { h32[o] = v0; h32[o + 1] = v1; }
        }
        // no drain, no flag: consumers poll the stored data; next step's poll
        // vmcnt(0) drains this store on our own wave.
    }
}

// ---------------------------------------------------------------- per-step fallback (coop launch fail)
__global__ __launch_bounds__(512) void rnn_step_f(
    const ushort_t* __restrict__ xh,   const ushort_t* __restrict__ xl,
    const ushort_t* __restrict__ wihh, const ushort_t* __restrict__ wihl,
    const ushort_t* __restrict__ whhh, const ushort_t* __restrict__ whhl,
    const ushort_t* __restrict__ hph,  ushort_t* __restrict__ hnh,
    const float* __restrict__ b_ih, const float* __restrict__ b_hh,
    float* __restrict__ h32, int t)
{
    __shared__ float red[8][16][66];
    const int tid = threadIdx.x;
    const int wv = tid >> 6, lane = tid & 63;
    const int row16 = lane & 15, kblk = lane >> 4;
    const int lid = blockIdx.x;
    const int rb = lid & 15, cb = lid >> 4;
    const int r0 = rb * 16, c0 = cb * 64;
    const size_t xcol = (size_t)wv * 32 + kblk * 8;

    f32x4 acc[4] = {};
    if (wv < 7) {
        const size_t xo = ((size_t)(r0 + row16) * TT + t) * II + xcol;
        short8 fxh = *(const short8*)(xh + xo);
        short8 fxl = *(const short8*)(xl + xo);
        #pragma unroll
        for (int n = 0; n < 4; ++n) {
            const size_t wo = (size_t)(c0 + n * 16 + row16) * II + xcol;
            short8 wiH = *(const short8*)(wihh + wo);
            short8 wiL = *(const short8*)(wihl + wo);
            acc[n] = MFMA(fxh, wiH, acc[n]);
            acc[n] = MFMA(fxh, wiL, acc[n]);
            acc[n] = MFMA(fxl, wiH, acc[n]);
        }
    }
    const size_t ha = (size_t)(r0 + row16) * HH + 128 * wv + kblk * 8;
    #pragma unroll
    for (int kb = 0; kb < 4; ++kb) {
        short8 fH = *(const short8*)(hph + ha + kb * 32);
        #pragma unroll
        for (int n = 0; n < 4; ++n) {
            const size_t wo = (size_t)(c0 + n * 16 + row16) * HH + 128 * wv + kb * 32 + kblk * 8;
            short8 wH = *(const short8*)(whhh + wo);
            short8 wL = *(const short8*)(whhl + wo);
            acc[n] = MFMA(fH, wH, acc[n]);
            acc[n] = MFMA(fH, wL, acc[n]);
        }
    }
    #pragma unroll
    for (int n = 0; n < 4; ++n)
        #pragma unroll
        for (int jj = 0; jj < 4; ++jj)
            red[wv][kblk * 4 + jj][n * 16 + row16] = acc[n][jj];
    __syncthreads();
    {
        const int erow = tid >> 5;
        const int ecp  = tid & 31;
        const int cg0  = c0 + 2 * ecp;
        float v0 = b_ih[cg0] + b_hh[cg0];
        float v1 = b_ih[cg0 + 1] + b_hh[cg0 + 1];
        #pragma unroll
        for (int w = 0; w < 8; ++w) {
            float2 rv = *(const float2*)&red[w][erow][2 * ecp];
            v0 += rv.x; v1 += rv.y;
        }
        v0 = tanhf(v0); v1 = tanhf(v1);
        const size_t o = (size_t)(r0 + erow) * HH + cg0;
        hnh[o] = bfbits(v0);  hnh[o + 1] = bfbits(v1);
        if (t == TT - 1) { h32[o] = v0; h32[o + 1] = v1; }
    }
}

// ---------------------------------------------------------------- FC
__global__ __launch_bounds__(256) void fc_kernel(
    const float* __restrict__ h, const float* __restrict__ W_fc,
    const float* __restrict__ b_fc, float* __restrict__ out)
{
    const int b = blockIdx.x;
    const int tid = threadIdx.x;
    float p[OO] = {0.f, 0.f, 0.f, 0.f};
    for (int k = tid; k < HH; k += 256) {
        float hv = h[(size_t)b * HH + k];
        #pragma unroll
        for (int o = 0; o < OO; ++o) p[o] += hv * W_fc[(size_t)o * HH + k];
    }
    #pragma unroll
    for (int off = 32; off > 0; off >>= 1) {
        #pragma unroll
        for (int o = 0; o < OO; ++o) p[o] += __shfl_down(p[o], off, 64);
    }
    __shared__ float red[4][OO];
    const int wave = tid >> 6, lane = tid & 63;
    if (lane == 0) {
        #pragma unroll
        for (int o = 0; o < OO; ++o) red[wave][o] = p[o];
    }
    __syncthreads();
    if (tid < OO) {
        float s = red[0][tid] + red[1][tid] + red[2][tid] + red[3][tid] + b_fc[tid];
        out[b * OO + tid] = s;
    }
}

// ---------------------------------------------------------------- launch
extern "C" void kernel_launch(void* const* d_in, const int* in_sizes, int n_in,
                              void* d_out, int out_size, void* d_ws, size_t ws_size,
                              hipStream_t stream) {
    const float* x    = (const float*)d_in[0];
    const float* W_ih = (const float*)d_in[1];
    const float* W_hh = (const float*)d_in[2];
    const float* b_ih = (const float*)d_in[3];
    const float* b_hh = (const float*)d_in[4];
    const float* W_fc = (const float*)d_in[5];
    const float* b_fc = (const float*)d_in[6];
    float* out = (float*)d_out;

    // ws layout (bytes)
    const size_t SZ_X    = (size_t)BB * TT * II * 2;     // 25.7 MB per plane
    const size_t SZ_WIH  = (size_t)HH * II * 2;
    const size_t SZ_WHH  = (size_t)HH * HH * 2;
    const size_t SZ_HP   = HPLANE * 2;                   // 512 KB per h plane
    const size_t OFF_XH   = 0;
    const size_t OFF_XL   = OFF_XH + SZ_X;
    const size_t OFF_WIHH = OFF_XL + SZ_X;
    const size_t OFF_WIHL = OFF_WIHH + SZ_WIH;
    const size_t OFF_WHHH = OFF_WIHL + SZ_WIH;
    const size_t OFF_WHHL = OFF_WHHH + SZ_WHH;
    const size_t OFF_HBUF = OFF_WHHL + SZ_WHH;           // 225 planes
    const size_t OFF_H32  = OFF_HBUF + (size_t)(TT + 1) * SZ_HP;
    const size_t NEED     = OFF_H32 + (size_t)BB * HH * 4;

    char* ws = (char*)d_ws;

    if (ws_size >= NEED) {
        ushort_t* xhp  = (ushort_t*)(ws + OFF_XH);
        ushort_t* xlp  = (ushort_t*)(ws + OFF_XL);
        ushort_t* wihh = (ushort_t*)(ws + OFF_WIHH);
        ushort_t* wihl = (ushort_t*)(ws + OFF_WIHL);
        ushort_t* whhh = (ushort_t*)(ws + OFF_WHHH);
        ushort_t* whhl = (ushort_t*)(ws + OFF_WHHL);
        ushort_t* hbuf = (ushort_t*)(ws + OFF_HBUF);
        float*    h32  = (float*)(ws + OFF_H32);

        // prep: hi/lo splits; plane 0 = zeros (initial h); planes 1..224 = sentinel
        split_hi_lo<<<1024, 256, 0, stream>>>(x, xhp, xlp, (BB * TT * II) / 4);
        split_hi_lo<<<128, 256, 0, stream>>>(W_ih, wihh, wihl, (HH * II) / 4);
        split_hi_lo<<<512, 256, 0, stream>>>(W_hh, whhh, whhl, (HH * HH) / 4);
        zero_kernel<<<(int)((SZ_HP / 4 + 255) / 256), 256, 0, stream>>>((float*)hbuf, (int)(SZ_HP / 4));
        fill_sentinel<<<2048, 256, 0, stream>>>((uintx4*)(hbuf + HPLANE),
                                                (size_t)TT * SZ_HP / 16);

        const float* bihp = b_ih;
        const float* bhhp = b_hh;
        void* args[] = {
            (void*)&xhp, (void*)&xlp, (void*)&wihh, (void*)&wihl,
            (void*)&whhh, (void*)&whhl, (void*)&hbuf,
            (void*)&bihp, (void*)&bhhp, (void*)&h32
        };
        hipError_t e = hipLaunchCooperativeKernel((void*)rnn_persist10,
                                                  dim3(256), dim3(512), args, 0, stream);
        if (e != hipSuccess) {
            // fallback: per-step loop (kernel boundaries provide coherence;
            // sentinel planes are fully overwritten before being read)
            for (int t = 0; t < TT; ++t) {
                rnn_step_f<<<256, 512, 0, stream>>>(
                    xhp, xlp, wihh, wihl, whhh, whhl,
                    hbuf + (size_t)t * HPLANE, hbuf + (size_t)(t + 1) * HPLANE,
                    b_ih, b_hh, h32, t);
            }
        }
        fc_kernel<<<BB, 256, 0, stream>>>(h32, W_fc, b_fc, out);
    }
    // (ws too small not expected: NEED ~176 MB, observed ws ~268 MB)
}